// Round 8
// baseline (380.896 us; speedup 1.0000x reference)
//
#include <hip/hip_runtime.h>

typedef __attribute__((ext_vector_type(4))) float f32x4;
typedef __attribute__((ext_vector_type(8))) short bf16x8;
typedef __attribute__((ext_vector_type(4))) short bf16x4;

#define MFMA16(a, b, c) __builtin_amdgcn_mfma_f32_16x16x32_bf16(a, b, c, 0, 0, 0)

// ws fragment offsets in shorts (bf16 elements)
#define W1F_OFF 0        // 16384 elems (M=256,K=64,  KT=2)
#define W2F_OFF 16384    // 65536 elems (M=256,K=256, KT=8)
#define CF_OFF  81920    // 65536 elems (M=256,K=256, KT=8)
#define W3F_OFF 147456   // 16384 elems (M=64, K=256, KT=8)

// Native bf16 cast (RTNE). Backend pattern-matches adjacent pairs into
// v_cvt_pk_bf16_f32 (m240: do NOT hand-write the asm - breaks scheduling).
__device__ __forceinline__ short f2bf(float f) {
  __bf16 b = (__bf16)f;
  return __builtin_bit_cast(short, b);
}

__device__ __forceinline__ void sp_sig(float z, float& h, float& s) {
  // softplus + sigmoid sharing one exp: t = 2^(-|z|*log2e)
  float a = fabsf(z);
#if __has_builtin(__builtin_amdgcn_exp2f)
  float t = __builtin_amdgcn_exp2f(a * -1.44269504f);
#else
  float t = __expf(-a);
#endif
  float o = 1.f + t;
#if __has_builtin(__builtin_amdgcn_rcpf)
  float r = __builtin_amdgcn_rcpf(o);
#else
  float r = 1.f / o;
#endif
#if __has_builtin(__builtin_amdgcn_logf)
  float l2 = __builtin_amdgcn_logf(o);          // log2(o)
#else
  float l2 = __logf(o) * 1.44269504f;
#endif
  h = fmaxf(z, 0.f) + 0.69314718f * l2;
  s = (z >= 0.f) ? r : 1.f - r;
}

// ---------------------------------------------------------------------------
// Prep: swizzle W1, W2, C = W2 .* (W1@W3)^T, W3 into MFMA A-fragment order.
// A[m][k] with m = mt*16 + (lane&15), k = kt*32 + (lane>>4)*8 + j
// ---------------------------------------------------------------------------
__global__ __launch_bounds__(512) void cnf_prep(const float* __restrict__ W1,
                                                const float* __restrict__ W2,
                                                const float* __restrict__ W3,
                                                short* __restrict__ ws) {
  int e = blockIdx.x * 512 + threadIdx.x;   // [0, 163840)
  int j = e & 7;
  int l = (e >> 3) & 63;
  int g = l >> 4, lm = l & 15;
  float val;
  if (e < 16384) {                          // W1 frag: [256 x 64]
    int t = e >> 9, kt = t & 1, mt = t >> 1;
    val = W1[(mt * 16 + lm) * 64 + kt * 32 + g * 8 + j];
  } else if (e < 81920) {                   // W2 frag: [256 x 256]
    int t = (e - 16384) >> 9, kt = t & 7, mt = t >> 3;
    val = W2[(mt * 16 + lm) * 256 + kt * 32 + g * 8 + j];
  } else if (e < 147456) {                  // C frag: C[m][k] = W2[m,k]*A2[k,m]
    int t = (e - 81920) >> 9, kt = t & 7, mt = t >> 3;
    int m = mt * 16 + lm, k = kt * 32 + g * 8 + j;
    float a2 = 0.f;
#pragma unroll 16
    for (int d = 0; d < 64; ++d) a2 += W1[k * 64 + d] * W3[d * 256 + m];
    val = W2[m * 256 + k] * a2;
  } else {                                  // W3 frag: [64 x 256]
    int t = (e - 147456) >> 9, kt = t & 7, mt = t >> 3;
    val = W3[(mt * 16 + lm) * 256 + kt * 32 + g * 8 + j];
  }
  ws[e] = f2bf(val);
}

// ---------------------------------------------------------------------------
// Main: 256 blocks x 512 threads (8 waves). LDS (132KB) limits us to
// 1 block/CU = 8 waves/CU = 2 waves/EU regardless of registers, so tell the
// allocator: amdgpu_waves_per_eu(2,2) -> 256-VGPR budget. (R7 spilled 537MB
// of scratch because the default 4-waves/EU target caps VGPRs at 128, and
// the bias-fragment registers pushed live state just past it.)
// ---------------------------------------------------------------------------
__global__ __launch_bounds__(512)
__attribute__((amdgpu_waves_per_eu(2, 2))) void cnf_main(
    const float* __restrict__ x, const float* __restrict__ ld_init,
    const float* __restrict__ b1g, const float* __restrict__ b2g,
    const float* __restrict__ b3g, const float* __restrict__ Tg,
    const short* __restrict__ ws, float* __restrict__ outy,
    float* __restrict__ outl) {
  __shared__ __align__(16) short w1f[16384];       // 32 KB persistent W1 frags
  __shared__ __align__(16) short w3f[16384];       // 32 KB persistent W3 frags
  __shared__ __align__(16) short ytL[32 * 88];     // stage input, bf16 [s][d]
  __shared__ __align__(16) short h1L[32 * 264];    // softplus(z1), [col][row]
  __shared__ __align__(16) short s1L_[32 * 264];   // sigmoid(z1)
  __shared__ __align__(16) short h2L[32 * 264];    // softplus(z2)
  __shared__ __align__(16) float dyL[32 * 68];     // dy f32 [s][d], stride 68
  __shared__ __align__(16) float trPT[32][12];     // trace partials [s][wv]

  const int tid = threadIdx.x;
  const int lane = tid & 63, wv = tid >> 6;        // 8 waves
  const int sl = tid >> 4, q = tid & 15;           // sample-local, d-chunk
  const int lg = lane >> 4, lm = lane & 15;
  const int ko8 = lg << 3;

  // Stage persistent weight fragments into LDS
  {
    const f32x4* s1p = (const f32x4*)(ws + W1F_OFF);
    f32x4* d1 = (f32x4*)w1f;
#pragma unroll
    for (int i = 0; i < 4; ++i) d1[tid + 512 * i] = s1p[tid + 512 * i];
    const f32x4* s3p = (const f32x4*)(ws + W3F_OFF);
    f32x4* d3 = (f32x4*)w3f;
#pragma unroll
    for (int i = 0; i < 4; ++i) d3[tid + 512 * i] = s3p[tid + 512 * i];
  }

  // Per-thread bias fragments (folded into MFMA acc init)
  const int row0a = (2 * wv + 0) * 16 + (lg << 2);
  const int row0b = (2 * wv + 1) * 16 + (lg << 2);
  const f32x4 bias1a = *(const f32x4*)&b1g[row0a];
  const f32x4 bias1b = *(const f32x4*)&b1g[row0b];
  const f32x4 bias2a = *(const f32x4*)&b2g[row0a];
  const f32x4 bias2b = *(const f32x4*)&b2g[row0b];
  const int m3 = wv & 3, c3 = wv >> 2;
  const f32x4 bias3 = *(const f32x4*)&b3g[m3 * 16 + (lg << 2)];

  const bf16x8* w2fG = (const bf16x8*)(ws + W2F_OFF);
  const bf16x8* cfG  = (const bf16x8*)(ws + CF_OFF);

  const int sg = blockIdx.x * 32 + sl;
  f32x4 y = *(const f32x4*)&x[sg * 64 + q * 4];
  float ld = ld_init[sg];
  const float dt = Tg[0] * 0.1f;                   // T / NUM_STEPS

  __syncthreads();

  auto dyn = [&](f32x4 yin, f32x4& dy, float& tr)
      __attribute__((always_inline)) {
    // stage input -> LDS (bf16)
    bf16x4 yb;
#pragma unroll
    for (int r = 0; r < 4; ++r) yb[r] = f2bf(yin[r]);
    *(bf16x4*)&ytL[sl * 88 + q * 4] = yb;
    __syncthreads();                               // B1: ytmp ready

    // ---- GEMM1: z1^T = W1 * ytmp^T  (K=64), acc init = b1
    f32x4 a00 = bias1a, a01 = bias1a, a10 = bias1b, a11 = bias1b;
#pragma unroll
    for (int kt = 0; kt < 2; ++kt) {
      bf16x8 A0 = *(const bf16x8*)&w1f[(((2 * wv + 0) * 2 + kt) * 64 + lane) * 8];
      bf16x8 A1 = *(const bf16x8*)&w1f[(((2 * wv + 1) * 2 + kt) * 64 + lane) * 8];
      bf16x8 B0 = *(const bf16x8*)&ytL[lm * 88 + kt * 32 + ko8];
      bf16x8 B1 = *(const bf16x8*)&ytL[(16 + lm) * 88 + kt * 32 + ko8];
      a00 = MFMA16(A0, B0, a00); a01 = MFMA16(A0, B1, a01);
      a10 = MFMA16(A1, B0, a10); a11 = MFMA16(A1, B1, a11);
    }
    {
      auto epi1 = [&](const f32x4& z4, int r0, int c)
          __attribute__((always_inline)) {
        int sc = c * 16 + lm;
        bf16x4 hh, ss;
#pragma unroll
        for (int r = 0; r < 4; ++r) {
          float h, s;
          sp_sig(z4[r], h, s);
          hh[r] = f2bf(h); ss[r] = f2bf(s);
        }
        *(bf16x4*)&h1L[sc * 264 + r0] = hh;
        *(bf16x4*)&s1L_[sc * 264 + r0] = ss;
      };
      epi1(a00, row0a, 0); epi1(a01, row0a, 1);
      epi1(a10, row0b, 0); epi1(a11, row0b, 1);
    }
    __syncthreads();                               // B2: h1, s1 ready

    // ---- GEMM2: z2^T = W2 * h1^T (K=256), acc init = b2
    f32x4 c00 = bias2a, c01 = bias2a, c10 = bias2b, c11 = bias2b;
#pragma unroll
    for (int kt = 0; kt < 8; ++kt) {
      bf16x8 A0 = w2fG[((2 * wv + 0) * 8 + kt) * 64 + lane];
      bf16x8 A1 = w2fG[((2 * wv + 1) * 8 + kt) * 64 + lane];
      bf16x8 B0 = *(const bf16x8*)&h1L[lm * 264 + kt * 32 + ko8];
      bf16x8 B1 = *(const bf16x8*)&h1L[(16 + lm) * 264 + kt * 32 + ko8];
      c00 = MFMA16(A0, B0, c00); c01 = MFMA16(A0, B1, c01);
      c10 = MFMA16(A1, B0, c10); c11 = MFMA16(A1, B1, c11);
    }
    f32x4 s200, s201, s210, s211;
    {
      auto epi2 = [&](const f32x4& z4, int r0, int c, f32x4& s2o)
          __attribute__((always_inline)) {
        int sc = c * 16 + lm;
        bf16x4 hh;
#pragma unroll
        for (int r = 0; r < 4; ++r) {
          float h, s;
          sp_sig(z4[r], h, s);
          hh[r] = f2bf(h); s2o[r] = s;
        }
        *(bf16x4*)&h2L[sc * 264 + r0] = hh;
      };
      epi2(c00, row0a, 0, s200); epi2(c01, row0a, 1, s201);
      epi2(c10, row0b, 0, s210); epi2(c11, row0b, 1, s211);
    }

    // ---- GEMMC: u^T = C * s1^T (K=256) — s1 ready since B2, overlaps epi2
    f32x4 u00 = {0,0,0,0}, u01 = {0,0,0,0}, u10 = {0,0,0,0}, u11 = {0,0,0,0};
#pragma unroll
    for (int kt = 0; kt < 8; ++kt) {
      bf16x8 A0 = cfG[((2 * wv + 0) * 8 + kt) * 64 + lane];
      bf16x8 A1 = cfG[((2 * wv + 1) * 8 + kt) * 64 + lane];
      bf16x8 B0 = *(const bf16x8*)&s1L_[lm * 264 + kt * 32 + ko8];
      bf16x8 B1 = *(const bf16x8*)&s1L_[(16 + lm) * 264 + kt * 32 + ko8];
      u00 = MFMA16(A0, B0, u00); u01 = MFMA16(A0, B1, u01);
      u10 = MFMA16(A1, B0, u10); u11 = MFMA16(A1, B1, u11);
    }
    float pl0 = 0.f, pl1 = 0.f;
#pragma unroll
    for (int r = 0; r < 4; ++r) {
      pl0 += u00[r] * s200[r] + u10[r] * s210[r];
      pl1 += u01[r] * s201[r] + u11[r] * s211[r];
    }
    pl0 += __shfl_xor(pl0, 16); pl0 += __shfl_xor(pl0, 32);
    pl1 += __shfl_xor(pl1, 16); pl1 += __shfl_xor(pl1, 32);
    if (lane < 16) { trPT[lane][wv] = pl0; trPT[16 + lane][wv] = pl1; }

    // ---- GEMM3: dy^T = W3 * h2^T (K=256), one 16x16 tile per wave
    f32x4 d3a = bias3;
#pragma unroll
    for (int kt = 0; kt < 8; ++kt) {
      bf16x8 A0 = *(const bf16x8*)&w3f[((m3 * 8 + kt) * 64 + lane) * 8];
      bf16x8 B0 = *(const bf16x8*)&h2L[(c3 * 16 + lm) * 264 + kt * 32 + ko8];
      d3a = MFMA16(A0, B0, d3a);
    }
    *(f32x4*)&dyL[(c3 * 16 + lm) * 68 + m3 * 16 + (lg << 2)] = d3a;
    __syncthreads();                               // B4: dy, trace ready

    dy = *(const f32x4*)&dyL[sl * 68 + q * 4];
    f32x4 t0 = *(const f32x4*)&trPT[sl][0];
    f32x4 t1 = *(const f32x4*)&trPT[sl][4];
    f32x4 ts = t0 + t1;
    tr = ts[0] + ts[1] + ts[2] + ts[3];
  };

  // Dormand-Prince 5(4), fixed 10 steps; dt premultiplied into coefficients
  const float A21 = dt * (1.f / 5.f);
  const float A31 = dt * (3.f / 40.f), A32 = dt * (9.f / 40.f);
  const float A41 = dt * (44.f / 45.f), A42 = dt * (-56.f / 15.f),
              A43 = dt * (32.f / 9.f);
  const float A51 = dt * (19372.f / 6561.f), A52 = dt * (-25360.f / 2187.f),
              A53 = dt * (64448.f / 6561.f), A54 = dt * (-212.f / 729.f);
  const float A61 = dt * (9017.f / 3168.f), A62 = dt * (-355.f / 33.f),
              A63 = dt * (46732.f / 5247.f), A64 = dt * (49.f / 176.f),
              A65 = dt * (-5103.f / 18656.f);
  const float C1 = dt * (35.f / 384.f), C3 = dt * (500.f / 1113.f),
              C4 = dt * (125.f / 192.f), C5 = dt * (-2187.f / 6784.f),
              C6 = dt * (11.f / 84.f);

  f32x4 k1, k2, k3, k4, k5, k6;
  float tr;
#pragma unroll 1
  for (int step = 0; step < 10; ++step) {
    dyn(y, k1, tr);                                          ld += C1 * tr;
    dyn(y + A21 * k1, k2, tr);
    dyn(y + A31 * k1 + A32 * k2, k3, tr);                    ld += C3 * tr;
    dyn(y + A41 * k1 + A42 * k2 + A43 * k3, k4, tr);         ld += C4 * tr;
    dyn(y + A51 * k1 + A52 * k2 + A53 * k3 + A54 * k4, k5, tr);
    ld += C5 * tr;
    dyn(y + A61 * k1 + A62 * k2 + A63 * k3 + A64 * k4 + A65 * k5, k6, tr);
    ld += C6 * tr;
    y = y + C1 * k1 + C3 * k3 + C4 * k4 + C5 * k5 + C6 * k6;
  }

  *(f32x4*)&outy[sg * 64 + q * 4] = y;
  if (q == 0) outl[sg] = ld;
}

extern "C" void kernel_launch(void* const* d_in, const int* in_sizes, int n_in,
                              void* d_out, int out_size, void* d_ws, size_t ws_size,
                              hipStream_t stream) {
  const float* x  = (const float*)d_in[0];
  const float* l0 = (const float*)d_in[1];
  const float* W1 = (const float*)d_in[2];
  const float* b1 = (const float*)d_in[3];
  const float* W2 = (const float*)d_in[4];
  const float* b2 = (const float*)d_in[5];
  const float* W3 = (const float*)d_in[6];
  const float* b3 = (const float*)d_in[7];
  const float* Tp = (const float*)d_in[8];
  short* ws = (short*)d_ws;

  cnf_prep<<<dim3(320), dim3(512), 0, stream>>>(W1, W2, W3, ws);

  float* outy = (float*)d_out;
  float* outl = outy + 8192 * 64;
  cnf_main<<<dim3(256), dim3(512), 0, stream>>>(x, l0, b1, b2, b3, Tp, ws,
                                                outy, outl);
}